// Round 13
// baseline (208.638 us; speedup 1.0000x reference)
//
#include <hip/hip_runtime.h>
#include <hip/hip_bf16.h>
#include <stdint.h>
#include <math.h>

#define D_MODEL 1024
#define NH 16
#define HD 64
#define BATCH 4
#define SEQ 2048
#define MTOT (BATCH*SEQ)   // 8192
#define NBH (BATCH*NH)     // 64

typedef __attribute__((ext_vector_type(8))) short short8;    // 8 bf16
typedef __attribute__((ext_vector_type(4))) short short4v;   // 4 bf16
typedef __attribute__((ext_vector_type(2))) unsigned uint2v;
typedef __attribute__((ext_vector_type(4))) unsigned uint4v;
typedef __attribute__((ext_vector_type(4))) float f32x4;
typedef __attribute__((ext_vector_type(16))) float f32x16;

static __device__ __forceinline__ unsigned short f2bf(float f) {
  union { float f; unsigned u; } v; v.f = f;
  unsigned r = v.u + 0x7FFFu + ((v.u >> 16) & 1u);   // RNE
  return (unsigned short)(r >> 16);
}

// HW packed f32x2 -> bf16x2 (RNE); no builtin on gfx950 -> inline asm (T12)
static __device__ __forceinline__ unsigned cvt_pk_bf16(float lo, float hi) {
  unsigned r;
  asm("v_cvt_pk_bf16_f32 %0, %1, %2" : "=v"(r) : "v"(lo), "v"(hi));
  return r;
}

static __device__ __forceinline__ float fexp2(float x) {
#if __has_builtin(__builtin_amdgcn_exp2f)
  return __builtin_amdgcn_exp2f(x);
#else
  return __expf(x * 0.69314718056f);
#endif
}

#define GLOAD16(g, l) __builtin_amdgcn_global_load_lds( \
    (const __attribute__((address_space(1))) unsigned int*)(g), \
    (__attribute__((address_space(3))) unsigned int*)(l), 16, 0, 0)

#define BAR() { asm volatile("" ::: "memory"); __builtin_amdgcn_s_barrier(); \
                asm volatile("" ::: "memory"); }

// ---------------------------------------------------------------------------
// K0: convert x and weights to bf16, build RoPE tables ([j][t], t fast).
// ---------------------------------------------------------------------------
__global__ __launch_bounds__(256) void k_prep(
    const float* __restrict__ x, const float* __restrict__ wq,
    const float* __restrict__ wk, const float* __restrict__ wv,
    const float* __restrict__ wo,
    unsigned short* __restrict__ xb, unsigned short* __restrict__ wb,
    float* __restrict__ cosT, float* __restrict__ sinT) {
  long i = (long)blockIdx.x * 256 + threadIdx.x;
  const long NX = (long)MTOT * D_MODEL;
  const long NW = (long)D_MODEL * D_MODEL;
  if (i < NX) { xb[i] = f2bf(x[i]); return; }
  i -= NX;
  if (i < NW) { wb[i] = f2bf(wq[i]); return; }
  i -= NW;
  if (i < NW) { wb[NW + i] = f2bf(wk[i]); return; }
  i -= NW;
  if (i < NW) { wb[2 * NW + i] = f2bf(wv[i]); return; }
  i -= NW;
  if (i < NW) { wb[3 * NW + i] = f2bf(wo[i]); return; }
  i -= NW;
  if (i < (long)SEQ * (HD / 2)) {
    int t = (int)(i & (SEQ - 1)), j = (int)(i >> 11);   // t fast -> coalesced
    float freq = 1.0f / powf(10000.0f, (float)j * (1.0f / 32.0f));
    float ang = (float)t * freq;
    cosT[j * SEQ + t] = cosf(ang);
    sinT[j * SEQ + t] = sinf(ang);
  }
}

// ---------------------------------------------------------------------------
// GEMM: C[m][n] = sum_k A[m][k] * Bw[n][k]
// THIS ROUND: 4-phase counted-vmcnt schedule (T3+T4+T5 on the proven T2
// swizzle). BK=64, dbuf LDS (64KB), 2 blocks/CU. Per K-tile: 4 phases of
// {stage chunk of tile t+1 | 8 ds_read_b128 | setprio + 8 MFMA | barrier}.
// vmcnt(4) at phase 0 only (t+1's A-chunk stays in flight -> counted, never
// drained in main loop); vmcnt(0) only on the last tile. Rows are 128B =
// 8 chunks; swizzle chunk^=(row&7), source pre-swizzled (rule #21).
// Hazards: leading barrier (after per-wave vmcnt) publishes all waves'
// loads; phase-3 barrier orders tile-t reads before tile-t+2 overwrites.
// EPI=0 (QKV): RoPE fused for q/k, V stored transposed. EPI=1: fp32 out.
// ---------------------------------------------------------------------------
#define MFMA16(a, b, c) __builtin_amdgcn_mfma_f32_16x16x32_bf16(a, b, c, 0, 0, 0)

template<int EPI>
__global__ __launch_bounds__(256) void k_gemm(
    const unsigned short* __restrict__ A, const unsigned short* __restrict__ Bw,
    unsigned short* __restrict__ q, unsigned short* __restrict__ k2,
    unsigned short* __restrict__ vt,
    const float* __restrict__ cosT, const float* __restrict__ sinT,
    float* __restrict__ outf) {
  __shared__ __align__(16) unsigned short As2[2][128 * 64];   // 32KB
  __shared__ __align__(16) unsigned short Bs2[2][128 * 64];   // 32KB
  const int tid = threadIdx.x;
  const int wid = tid >> 6, lane = tid & 63;
  const int l15 = lane & 15, lq = lane >> 4;
  const int m0 = blockIdx.x * 128, n0 = blockIdx.y * 128;
  const int wm = (wid >> 1) * 64, wn = (wid & 1) * 64;

  const f32x4 fz = {0.f, 0.f, 0.f, 0.f};
  f32x4 acc[4][4];
#pragma unroll
  for (int i = 0; i < 4; ++i)
#pragma unroll
    for (int j = 0; j < 4; ++j) acc[i][j] = fz;

  // staging: granule g = tid + s*256 -> row = (tid>>3)+32s, chunk = tid&7.
  // source chunk pre-swizzled: cs = c ^ (row&7); (row&7) const across s.
  const int sr = tid >> 3;                     // 0..31
  const int cs = (tid & 7) ^ (sr & 7);
  const unsigned short* Ag = A + (long)(m0 + sr) * D_MODEL + cs * 8;
  const unsigned short* Bg = Bw + (long)(n0 + sr) * D_MODEL + cs * 8;

#define SA0(t_) { const long ko = (long)(t_) * 64; \
    unsigned short* d = As2[(t_) & 1] + wid * 512; \
    GLOAD16(Ag + ko, d); GLOAD16(Ag + ko + 32 * D_MODEL, d + 2048); }
#define SA1(t_) { const long ko = (long)(t_) * 64; \
    unsigned short* d = As2[(t_) & 1] + wid * 512; \
    GLOAD16(Ag + ko + 64 * D_MODEL, d + 4096); \
    GLOAD16(Ag + ko + 96 * D_MODEL, d + 6144); }
#define SB0(t_) { const long ko = (long)(t_) * 64; \
    unsigned short* d = Bs2[(t_) & 1] + wid * 512; \
    GLOAD16(Bg + ko, d); GLOAD16(Bg + ko + 32 * D_MODEL, d + 2048); }
#define SB1(t_) { const long ko = (long)(t_) * 64; \
    unsigned short* d = Bs2[(t_) & 1] + wid * 512; \
    GLOAD16(Bg + ko + 64 * D_MODEL, d + 4096); \
    GLOAD16(Bg + ko + 96 * D_MODEL, d + 6144); }

  // phase: 2x2 acc quadrant x full BK=64 (kk in {0,1} -> chunk kk*4+lq)
#define PHASE(I0, J0) do { \
    const int ra0 = wm + (I0) * 16 + l15, ra1 = ra0 + 16; \
    const int rx0 = ra0 & 7, rx1 = ra1 & 7; \
    const short8 a00 = *(const short8*)(Ab + (ra0 << 7) + ((lq ^ rx0) << 4)); \
    const short8 a01 = *(const short8*)(Ab + (ra0 << 7) + (((4 | lq) ^ rx0) << 4)); \
    const short8 a10 = *(const short8*)(Ab + (ra1 << 7) + ((lq ^ rx1) << 4)); \
    const short8 a11 = *(const short8*)(Ab + (ra1 << 7) + (((4 | lq) ^ rx1) << 4)); \
    const int rb0 = wn + (J0) * 16 + l15, rb1 = rb0 + 16; \
    const int sx0 = rb0 & 7, sx1 = rb1 & 7; \
    const short8 b00 = *(const short8*)(Bb + (rb0 << 7) + ((lq ^ sx0) << 4)); \
    const short8 b01 = *(const short8*)(Bb + (rb0 << 7) + (((4 | lq) ^ sx0) << 4)); \
    const short8 b10 = *(const short8*)(Bb + (rb1 << 7) + ((lq ^ sx1) << 4)); \
    const short8 b11 = *(const short8*)(Bb + (rb1 << 7) + (((4 | lq) ^ sx1) << 4)); \
    __builtin_amdgcn_s_setprio(1); \
    acc[(I0)][(J0)]         = MFMA16(a00, b00, acc[(I0)][(J0)]); \
    acc[(I0)][(J0)]         = MFMA16(a01, b01, acc[(I0)][(J0)]); \
    acc[(I0)][(J0) + 1]     = MFMA16(a00, b10, acc[(I0)][(J0) + 1]); \
    acc[(I0)][(J0) + 1]     = MFMA16(a01, b11, acc[(I0)][(J0) + 1]); \
    acc[(I0) + 1][(J0)]     = MFMA16(a10, b00, acc[(I0) + 1][(J0)]); \
    acc[(I0) + 1][(J0)]     = MFMA16(a11, b01, acc[(I0) + 1][(J0)]); \
    acc[(I0) + 1][(J0) + 1] = MFMA16(a10, b10, acc[(I0) + 1][(J0) + 1]); \
    acc[(I0) + 1][(J0) + 1] = MFMA16(a11, b11, acc[(I0) + 1][(J0) + 1]); \
    __builtin_amdgcn_s_setprio(0); \
  } while (0)

  SA0(0); SA1(0); SB0(0); SB1(0);              // 8 loads in flight
  const int NT = D_MODEL / 64;                 // 16
  for (int t = 0; t < NT; ++t) {
    const char* Ab = (const char*)As2[t & 1];
    const char* Bb = (const char*)Bs2[t & 1];
    if (t + 1 < NT) {
      SA0(t + 1); SA1(t + 1);                  // +4 -> <=12 outstanding
      asm volatile("s_waitcnt vmcnt(4)" ::: "memory");   // tile-t all landed
    } else {
      asm volatile("s_waitcnt vmcnt(0)" ::: "memory");   // last tile: drain
    }
    BAR();                                     // publish loads block-wide
    PHASE(0, 0);
    BAR();
    if (t + 1 < NT) SB0(t + 1);                // +2
    PHASE(2, 0);
    BAR();
    if (t + 1 < NT) SB1(t + 1);                // +2 (>=2 phases of lead)
    PHASE(0, 2);
    BAR();
    PHASE(2, 2);
    BAR();                                     // tile-t reads done before t+2 writes
  }
#undef SA0
#undef SA1
#undef SB0
#undef SB1
#undef PHASE

#pragma unroll
  for (int i = 0; i < 4; ++i) {
#pragma unroll
    for (int j = 0; j < 4; ++j) {
      if (EPI == 1) {
#pragma unroll
        for (int r = 0; r < 4; ++r) {
          const int m = m0 + wm + i * 16 + lq * 4 + r;
          const int n = n0 + wn + j * 16 + l15;
          outf[(long)m * D_MODEL + n] = acc[i][j][r];
        }
      } else {
        const int n = n0 + wn + j * 16 + l15;       // sel uniform over wave
        const int sel = n >> 10, nl = n & 1023;
        const int hh = nl >> 6, dd = nl & 63;
        const int mb = m0 + wm + i * 16 + lq * 4;   // 4 consecutive t
        const int bb = mb >> 11, t0 = mb & (SEQ - 1);
        const long bh = (long)bb * NH + hh;
        if (sel == 2) {
          uint2v pk;
          pk[0] = cvt_pk_bf16(acc[i][j][0], acc[i][j][1]);
          pk[1] = cvt_pk_bf16(acc[i][j][2], acc[i][j][3]);
          *(uint2v*)(vt + (bh * HD + dd) * SEQ + t0) = pk;   // V^T: [bh][d][t]
        } else {
          unsigned short* dst = (sel == 0) ? q : k2;
          const float qs = (sel == 0) ? 0.18033688011112793f : 1.0f;  // 0.125*log2e
          const float sgn = (dd & 1) ? 1.f : -1.f;
          const int jt = dd >> 1;
          const f32x4 cv = *(const f32x4*)(cosT + jt * SEQ + t0);
          const f32x4 sv = *(const f32x4*)(sinT + jt * SEQ + t0);
#pragma unroll
          for (int r = 0; r < 4; ++r) {
            const float val = acc[i][j][r];
            const float p = __shfl_xor(val, 1);     // RoPE pair partner (n^1)
            dst[((bh * SEQ + t0 + r) << 6) + dd] = f2bf((val * cv[r] + sgn * sv[r] * p) * qs);
          }
        }
      }
    }
  }
}

// ---------------------------------------------------------------------------
// K4: causal flash attention, swapped-operand, 32x32x16 MFMA, in-register P,
// counted-vmcnt dual-barrier schedule + makespan-constant remap (R10, proven).
// ---------------------------------------------------------------------------
__global__ __launch_bounds__(256, 3) void k_attn(
    const unsigned short* __restrict__ qb, const unsigned short* __restrict__ kb,
    const unsigned short* __restrict__ vt, unsigned short* __restrict__ ctx) {
  __shared__ __align__(16) unsigned short Ks[2][4096];   // [64 kv][64 d] swizzled
  __shared__ __align__(16) unsigned short Vs[2][4096];   // [64 d][64 kv] swizzled

  // makespan-constant remap (bijective orig -> (bh, blk))
  const int orig = blockIdx.x;                 // 0..1023
  const int c = orig & 255, rr = orig >> 8;    // co-resident group, round
  const int x = c & 7, y = c >> 3;             // XCD slot, class
  const int u = y & 3, g = y >> 2;
  const int bh = x * 8 + g;                    // 8 bh per XCD slot
  const int blk = (rr & 1) ? (15 - ((rr >> 1) << 2) - u)
                           : (u + ((rr >> 1) << 2));   // {u,15-u,u+4,11-u}
  const int ntB = 2 * blk + 2;

  const int tid = threadIdx.x;
  const int wid = tid >> 6, lane = tid & 63;
  const int l31 = lane & 31, hi = lane >> 5;
  const int qrow0w = blk * 128 + wid * 32;
  const int qg = qrow0w + l31;                 // this lane's q row

  const unsigned short* Kg = kb + ((long)bh * SEQ << 6);
  const unsigned short* Vg = vt + (long)bh * HD * SEQ;

  const int r0 = tid >> 3, c0 = tid & 7;
  const int r1 = r0 + 32;
  const int cs = c0 ^ (r0 & 7);                // r1&7 == r0&7

  const unsigned short* Qrow = qb + (((long)bh * SEQ + qrow0w + l31) << 6);
  short8 bq[4];
#pragma unroll
  for (int kbI = 0; kbI < 4; ++kbI)
    bq[kbI] = *(const short8*)(Qrow + kbI * 16 + hi * 8);

  f32x16 ota[2];                               // O^T: d = 32*a2 + (r&3)+8(r>>2)+4hi, q = l31
#pragma unroll
  for (int a2 = 0; a2 < 2; ++a2)
#pragma unroll
    for (int r = 0; r < 16; ++r) ota[a2][r] = 0.f;
  float m = -INFINITY, lsum = 0.f;

#define STAGE(t_) { \
    const long kv0s = (long)((t_) << 6); \
    unsigned short* kd = Ks[(t_) & 1]; \
    unsigned short* vd = Vs[(t_) & 1]; \
    GLOAD16(Kg + ((kv0s + r0) << 6) + (cs << 3), kd + wid * 512); \
    GLOAD16(Kg + ((kv0s + r1) << 6) + (cs << 3), kd + 2048 + wid * 512); \
    GLOAD16(Vg + (long)r0 * SEQ + kv0s + (cs << 3), vd + wid * 512); \
    GLOAD16(Vg + (long)r1 * SEQ + kv0s + (cs << 3), vd + 2048 + wid * 512); \
  }

  STAGE(0);

  for (int t = 0; t < ntB; ++t) {
    const int kv0 = t << 6;
    if (t + 1 < ntB) {
      STAGE(t + 1);                            // 4 more loads -> <=8 in flight
      asm volatile("s_waitcnt vmcnt(4)" ::: "memory");   // own tile-t landed
    } else {
      asm volatile("s_waitcnt vmcnt(0)" ::: "memory");   // last tile: drain
    }
    __builtin_amdgcn_s_barrier();              // all waves' tile-t loads landed

    if (kv0 <= qrow0w + 31) {                  // wave-uniform active guard
      const char* Kb = (const char*)Ks[t & 1];
      const char* Vb = (const char*)Vs[t & 1];

      f32x16 sa[2];
#pragma unroll
      for (int i = 0; i < 2; ++i)
#pragma unroll
        for (int r = 0; r < 16; ++r) sa[i][r] = 0.f;

      __builtin_amdgcn_s_setprio(1);
#pragma unroll
      for (int i = 0; i < 2; ++i) {
        const int row = 32 * i + l31;          // kv row in tile
        const int rb = row << 7, rx = row & 7;
#pragma unroll
        for (int kbI = 0; kbI < 4; ++kbI) {
          const short8 ak = *(const short8*)(Kb + rb + ((((kbI << 1) | hi) ^ rx) << 4));
          sa[i] = __builtin_amdgcn_mfma_f32_32x32x16_bf16(ak, bq[kbI], sa[i], 0, 0, 0);
        }
      }
      __builtin_amdgcn_s_setprio(0);

      if (kv0 + 63 > qrow0w) {
#pragma unroll
        for (int i = 0; i < 2; ++i) {
          const int kvb = kv0 + 32 * i + 4 * hi;
#pragma unroll
          for (int r = 0; r < 16; ++r)
            if (kvb + (r & 3) + 8 * (r >> 2) > qg) sa[i][r] = -INFINITY;
        }
      }

      float tmax = sa[0][0];
#pragma unroll
      for (int i = 0; i < 2; ++i)
#pragma unroll
        for (int r = 0; r < 16; ++r) tmax = fmaxf(tmax, sa[i][r]);
      tmax = fmaxf(tmax, __shfl_xor(tmax, 32));
      if (!__all(tmax <= m + 8.0f)) {
        const float mn = fmaxf(m, tmax);
        const float al = fexp2(m - mn);
        m = mn;
        lsum *= al;
#pragma unroll
        for (int a2 = 0; a2 < 2; ++a2)
#pragma unroll
          for (int r = 0; r < 16; ++r) ota[a2][r] *= al;
      }
      float rs = 0.f;
#pragma unroll
      for (int i = 0; i < 2; ++i)
#pragma unroll
        for (int r = 0; r < 16; ++r) {
          const float p = fexp2(sa[i][r] - m);
          sa[i][r] = p;
          rs += p;
        }
      rs += __shfl_xor(rs, 32);
      lsum += rs;

      short8 bp[4];
#pragma unroll
      for (int i = 0; i < 2; ++i)
#pragma unroll
        for (int jh = 0; jh < 2; ++jh) {
          const int bs = 8 * jh;
          const unsigned x0 = cvt_pk_bf16(sa[i][bs + 0], sa[i][bs + 1]);
          const unsigned y0 = cvt_pk_bf16(sa[i][bs + 4], sa[i][bs + 5]);
          const unsigned x1 = cvt_pk_bf16(sa[i][bs + 2], sa[i][bs + 3]);
          const unsigned y1 = cvt_pk_bf16(sa[i][bs + 6], sa[i][bs + 7]);
          const uint2v s0 = __builtin_amdgcn_permlane32_swap(x0, y0, false, false);
          const uint2v s1 = __builtin_amdgcn_permlane32_swap(x1, y1, false, false);
          union { uint4v u4; short8 s; } bb;
          bb.u4[0] = s0[0]; bb.u4[1] = s1[0]; bb.u4[2] = s0[1]; bb.u4[3] = s1[1];
          bp[2 * i + jh] = bb.s;
        }

      __builtin_amdgcn_s_setprio(1);
#pragma unroll
      for (int a2 = 0; a2 < 2; ++a2) {
        const int row = 32 * a2 + l31;         // d row
        const int rb = row << 7, rx = row & 7;
#pragma unroll
        for (int kf = 0; kf < 4; ++kf) {
          const short8 av = *(const short8*)(Vb + rb + ((((kf << 1) | hi) ^ rx) << 4));
          ota[a2] = __builtin_amdgcn_mfma_f32_32x32x16_bf16(av, bp[kf], ota[a2], 0, 0, 0);
        }
      }
      __builtin_amdgcn_s_setprio(0);
    }

    asm volatile("" ::: "memory");             // keep ds_reads on this side
    __builtin_amdgcn_s_barrier();              // WAR: reads done before next STAGE
  }
#undef STAGE

  const int b = bh >> 4, h = bh & 15;
  unsigned short* cb = ctx + (((long)b * SEQ) << 10) + (h << 6);
  const float inv = 1.0f / lsum;
  const long trow = qg;
#pragma unroll
  for (int a2 = 0; a2 < 2; ++a2)
#pragma unroll
    for (int rb4 = 0; rb4 < 4; ++rb4) {
      const int d0 = 32 * a2 + 8 * rb4 + 4 * hi;
      uint2v pk;
      pk[0] = cvt_pk_bf16(ota[a2][4 * rb4 + 0] * inv, ota[a2][4 * rb4 + 1] * inv);
      pk[1] = cvt_pk_bf16(ota[a2][4 * rb4 + 2] * inv, ota[a2][4 * rb4 + 3] * inv);
      *(uint2v*)(cb + trow * D_MODEL + d0) = pk;
    }
}

// ---------------------------------------------------------------------------
extern "C" void kernel_launch(void* const* d_in, const int* in_sizes, int n_in,
                              void* d_out, int out_size, void* d_ws, size_t ws_size,
                              hipStream_t stream) {
  const float* x  = (const float*)d_in[0];
  const float* wq = (const float*)d_in[1];
  const float* wk = (const float*)d_in[2];
  const float* wv = (const float*)d_in[3];
  const float* wo = (const float*)d_in[4];
  float* out = (float*)d_out;
  char* ws = (char*)d_ws;

  unsigned short* xb  = (unsigned short*)(ws);                 // 16 MB (x bf16; reused as ctx)
  unsigned short* wb  = (unsigned short*)(ws + (16l << 20));   // 8 MB  (Wq|Wk|Wv|Wo bf16)
  unsigned short* qb  = (unsigned short*)(ws + (24l << 20));   // 16 MB [bh][t][d]
  unsigned short* kb  = (unsigned short*)(ws + (40l << 20));   // 16 MB [bh][t][d]
  unsigned short* vt  = (unsigned short*)(ws + (56l << 20));   // 16 MB [bh][d][t]
  float* cosT = (float*)(ws + (72l << 20));                    // 256 KB [j][t]
  float* sinT = cosT + SEQ * 32;                               // 256 KB [j][t]
  unsigned short* ctx = xb;   // xb dead after QKV GEMM

  const long ntot = (long)MTOT * D_MODEL + 4l * D_MODEL * D_MODEL + (long)SEQ * 32;
  k_prep<<<dim3((unsigned)((ntot + 255) / 256)), dim3(256), 0, stream>>>(
      x, wq, wk, wv, wo, xb, wb, cosT, sinT);
  k_gemm<0><<<dim3(64, 24), dim3(256), 0, stream>>>(
      xb, wb, qb, kb, vt, cosT, sinT, nullptr);
  k_attn<<<dim3(1024), dim3(256), 0, stream>>>(qb, kb, vt, ctx);
  k_gemm<1><<<dim3(64, 8), dim3(256), 0, stream>>>(
      ctx, wb + 3l * D_MODEL * D_MODEL, nullptr, nullptr, nullptr, nullptr, nullptr, out);
}

// Round 14
// 161.042 us; speedup vs baseline: 1.2955x; 1.2955x over previous
//
#include <hip/hip_runtime.h>
#include <hip/hip_bf16.h>
#include <stdint.h>
#include <math.h>

#define D_MODEL 1024
#define NH 16
#define HD 64
#define BATCH 4
#define SEQ 2048
#define MTOT (BATCH*SEQ)   // 8192
#define NBH (BATCH*NH)     // 64

typedef __attribute__((ext_vector_type(8))) short short8;    // 8 bf16
typedef __attribute__((ext_vector_type(4))) short short4v;   // 4 bf16
typedef __attribute__((ext_vector_type(2))) unsigned uint2v;
typedef __attribute__((ext_vector_type(4))) unsigned uint4v;
typedef __attribute__((ext_vector_type(4))) float f32x4;
typedef __attribute__((ext_vector_type(16))) float f32x16;

static __device__ __forceinline__ unsigned short f2bf(float f) {
  union { float f; unsigned u; } v; v.f = f;
  unsigned r = v.u + 0x7FFFu + ((v.u >> 16) & 1u);   // RNE
  return (unsigned short)(r >> 16);
}

// HW packed f32x2 -> bf16x2 (RNE); no builtin on gfx950 -> inline asm (T12)
static __device__ __forceinline__ unsigned cvt_pk_bf16(float lo, float hi) {
  unsigned r;
  asm("v_cvt_pk_bf16_f32 %0, %1, %2" : "=v"(r) : "v"(lo), "v"(hi));
  return r;
}

static __device__ __forceinline__ float fexp2(float x) {
#if __has_builtin(__builtin_amdgcn_exp2f)
  return __builtin_amdgcn_exp2f(x);
#else
  return __expf(x * 0.69314718056f);
#endif
}

#define GLOAD16(g, l) __builtin_amdgcn_global_load_lds( \
    (const __attribute__((address_space(1))) unsigned int*)(g), \
    (__attribute__((address_space(3))) unsigned int*)(l), 16, 0, 0)

// ---------------------------------------------------------------------------
// K0: convert x and weights to bf16 (float4 loads, packed bf16x2 stores —
// 16B/lane in, 8B/lane out), build RoPE tables ([j][t], t fast).
// Conversion slice: 3,145,728 threads x 4 elems; table slice: 65,536 threads.
// ---------------------------------------------------------------------------
#define NCONV_THREADS 3145728   // (MTOT*D_MODEL + 4*D_MODEL*D_MODEL) / 4
__global__ __launch_bounds__(256) void k_prep(
    const float* __restrict__ x, const float* __restrict__ wq,
    const float* __restrict__ wk, const float* __restrict__ wv,
    const float* __restrict__ wo,
    unsigned short* __restrict__ xb, unsigned short* __restrict__ wb,
    float* __restrict__ cosT, float* __restrict__ sinT) {
  const long gid = (long)blockIdx.x * 256 + threadIdx.x;
  const long NX = (long)MTOT * D_MODEL;      // 8388608
  const long NW = (long)D_MODEL * D_MODEL;   // 1048576
  if (gid < NCONV_THREADS) {
    const long e0 = gid << 2;                // first of 4 elements
    const float* src;
    unsigned short* dst;
    if (e0 < NX) {
      src = x + e0;
      dst = xb + e0;
    } else {
      const long j = e0 - NX;                // 0 .. 4*NW-1
      const int w = (int)(j >> 20);          // NW = 2^20
      const long off = j & (NW - 1);
      src = (w == 0 ? wq : w == 1 ? wk : w == 2 ? wv : wo) + off;
      dst = wb + j;                          // wb = [Wq|Wk|Wv|Wo] contiguous
    }
    const f32x4 v = *(const f32x4*)src;
    uint2v pk;
    pk[0] = cvt_pk_bf16(v[0], v[1]);
    pk[1] = cvt_pk_bf16(v[2], v[3]);
    *(uint2v*)dst = pk;
    return;
  }
  const long tt = gid - NCONV_THREADS;       // 0 .. SEQ*32-1
  if (tt < (long)SEQ * 32) {
    const int t = (int)(tt & (SEQ - 1)), j = (int)(tt >> 11);
    const float freq = 1.0f / powf(10000.0f, (float)j * (1.0f / 32.0f));
    const float ang = (float)t * freq;
    cosT[j * SEQ + t] = cosf(ang);
    sinT[j * SEQ + t] = sinf(ang);
  }
}

// ---------------------------------------------------------------------------
// GEMM: C[m][n] = sum_k A[m][k] * Bw[n][k]     (R12-exact, proven 76us)
// Conflict-free LDS swizzle (T2/rule#21): rows are 64B (4 chunks of 16B);
// swizzled chunk c' = c ^ ((row>>1)&3); LDS dest linear (global_load_lds),
// global SOURCE pre-swizzled, ds_read applies the same XOR. Bank conflicts
// measured 0. EPI=0 (QKV): RoPE fused, V stored transposed. EPI=1: fp32 out.
// ---------------------------------------------------------------------------
template<int EPI>
__global__ __launch_bounds__(256) void k_gemm(
    const unsigned short* __restrict__ A, const unsigned short* __restrict__ Bw,
    unsigned short* __restrict__ q, unsigned short* __restrict__ k2,
    unsigned short* __restrict__ vt,
    const float* __restrict__ cosT, const float* __restrict__ sinT,
    float* __restrict__ outf) {
  __shared__ __align__(16) unsigned short As[128 * 32];
  __shared__ __align__(16) unsigned short Bs[128 * 32];
  const int tid = threadIdx.x;
  const int wid = tid >> 6, lane = tid & 63;
  const int l15 = lane & 15, lq = lane >> 4;
  const int m0 = blockIdx.x * 128, n0 = blockIdx.y * 128;
  const int wm = (wid >> 1) * 64, wn = (wid & 1) * 64;

  const f32x4 fz = {0.f, 0.f, 0.f, 0.f};
  f32x4 acc[4][4];
#pragma unroll
  for (int i = 0; i < 4; ++i)
#pragma unroll
    for (int j = 0; j < 4; ++j) acc[i][j] = fz;

  // staging: row srow (+64 for second granule); source chunk pre-swizzled.
  const int srow = wid * 16 + (lane >> 2);
  const int scs = (lane & 3) ^ ((srow >> 1) & 3);
  const unsigned short* Ag = A + (long)(m0 + srow) * D_MODEL + scs * 8;
  const unsigned short* Bg = Bw + (long)(n0 + srow) * D_MODEL + scs * 8;

  const int rsw = (l15 >> 1) & 3;   // read-side row swizzle key

  for (int k0 = 0; k0 < D_MODEL; k0 += 32) {
    GLOAD16(Ag + k0, As + wid * 512);
    GLOAD16(Ag + k0 + 64 * D_MODEL, As + 2048 + wid * 512);
    GLOAD16(Bg + k0, Bs + wid * 512);
    GLOAD16(Bg + k0 + 64 * D_MODEL, Bs + 2048 + wid * 512);
    __syncthreads();

    short8 af[4], bf[4];
#pragma unroll
    for (int i = 0; i < 4; ++i) {
      af[i] = *(const short8*)(As + (wm + i * 16 + l15) * 32 + ((lq ^ rsw) << 3));
      bf[i] = *(const short8*)(Bs + (wn + i * 16 + l15) * 32 + ((lq ^ rsw) << 3));
    }
#pragma unroll
    for (int i = 0; i < 4; ++i)
#pragma unroll
      for (int j = 0; j < 4; ++j)
        acc[i][j] = __builtin_amdgcn_mfma_f32_16x16x32_bf16(af[i], bf[j], acc[i][j], 0, 0, 0);
    __syncthreads();
  }

#pragma unroll
  for (int i = 0; i < 4; ++i) {
#pragma unroll
    for (int j = 0; j < 4; ++j) {
      if (EPI == 1) {
#pragma unroll
        for (int r = 0; r < 4; ++r) {
          const int m = m0 + wm + i * 16 + lq * 4 + r;
          const int n = n0 + wn + j * 16 + l15;
          outf[(long)m * D_MODEL + n] = acc[i][j][r];
        }
      } else {
        const int n = n0 + wn + j * 16 + l15;       // sel uniform over wave
        const int sel = n >> 10, nl = n & 1023;
        const int hh = nl >> 6, dd = nl & 63;
        const int mb = m0 + wm + i * 16 + lq * 4;   // 4 consecutive t
        const int bb = mb >> 11, t0 = mb & (SEQ - 1);
        const long bh = (long)bb * NH + hh;
        if (sel == 2) {
          uint2v pk;
          pk[0] = cvt_pk_bf16(acc[i][j][0], acc[i][j][1]);
          pk[1] = cvt_pk_bf16(acc[i][j][2], acc[i][j][3]);
          *(uint2v*)(vt + (bh * HD + dd) * SEQ + t0) = pk;   // V^T: [bh][d][t]
        } else {
          unsigned short* dst = (sel == 0) ? q : k2;
          const float qs = (sel == 0) ? 0.18033688011112793f : 1.0f;  // 0.125*log2e
          const float sgn = (dd & 1) ? 1.f : -1.f;
          const int jt = dd >> 1;
          const f32x4 cv = *(const f32x4*)(cosT + jt * SEQ + t0);
          const f32x4 sv = *(const f32x4*)(sinT + jt * SEQ + t0);
#pragma unroll
          for (int r = 0; r < 4; ++r) {
            const float val = acc[i][j][r];
            const float p = __shfl_xor(val, 1);     // RoPE pair partner (n^1)
            dst[((bh * SEQ + t0 + r) << 6) + dd] = f2bf((val * cv[r] + sgn * sv[r] * p) * qs);
          }
        }
      }
    }
  }
}

// ---------------------------------------------------------------------------
// K4: causal flash attention, swapped-operand, 32x32x16 MFMA, in-register P,
// counted-vmcnt dual-barrier schedule + makespan-constant remap (R10, proven).
// ---------------------------------------------------------------------------
__global__ __launch_bounds__(256, 3) void k_attn(
    const unsigned short* __restrict__ qb, const unsigned short* __restrict__ kb,
    const unsigned short* __restrict__ vt, unsigned short* __restrict__ ctx) {
  __shared__ __align__(16) unsigned short Ks[2][4096];   // [64 kv][64 d] swizzled
  __shared__ __align__(16) unsigned short Vs[2][4096];   // [64 d][64 kv] swizzled

  // makespan-constant remap (bijective orig -> (bh, blk))
  const int orig = blockIdx.x;                 // 0..1023
  const int c = orig & 255, rr = orig >> 8;    // co-resident group, round
  const int x = c & 7, y = c >> 3;             // XCD slot, class
  const int u = y & 3, g = y >> 2;
  const int bh = x * 8 + g;                    // 8 bh per XCD slot
  const int blk = (rr & 1) ? (15 - ((rr >> 1) << 2) - u)
                           : (u + ((rr >> 1) << 2));   // {u,15-u,u+4,11-u}
  const int ntB = 2 * blk + 2;

  const int tid = threadIdx.x;
  const int wid = tid >> 6, lane = tid & 63;
  const int l31 = lane & 31, hi = lane >> 5;
  const int qrow0w = blk * 128 + wid * 32;
  const int qg = qrow0w + l31;                 // this lane's q row

  const unsigned short* Kg = kb + ((long)bh * SEQ << 6);
  const unsigned short* Vg = vt + (long)bh * HD * SEQ;

  const int r0 = tid >> 3, c0 = tid & 7;
  const int r1 = r0 + 32;
  const int cs = c0 ^ (r0 & 7);                // r1&7 == r0&7

  const unsigned short* Qrow = qb + (((long)bh * SEQ + qrow0w + l31) << 6);
  short8 bq[4];
#pragma unroll
  for (int kbI = 0; kbI < 4; ++kbI)
    bq[kbI] = *(const short8*)(Qrow + kbI * 16 + hi * 8);

  f32x16 ota[2];                               // O^T: d = 32*a2 + (r&3)+8(r>>2)+4hi, q = l31
#pragma unroll
  for (int a2 = 0; a2 < 2; ++a2)
#pragma unroll
    for (int r = 0; r < 16; ++r) ota[a2][r] = 0.f;
  float m = -INFINITY, lsum = 0.f;

#define STAGE(t_) { \
    const long kv0s = (long)((t_) << 6); \
    unsigned short* kd = Ks[(t_) & 1]; \
    unsigned short* vd = Vs[(t_) & 1]; \
    GLOAD16(Kg + ((kv0s + r0) << 6) + (cs << 3), kd + wid * 512); \
    GLOAD16(Kg + ((kv0s + r1) << 6) + (cs << 3), kd + 2048 + wid * 512); \
    GLOAD16(Vg + (long)r0 * SEQ + kv0s + (cs << 3), vd + wid * 512); \
    GLOAD16(Vg + (long)r1 * SEQ + kv0s + (cs << 3), vd + 2048 + wid * 512); \
  }

  STAGE(0);

  for (int t = 0; t < ntB; ++t) {
    const int kv0 = t << 6;
    if (t + 1 < ntB) {
      STAGE(t + 1);                            // 4 more loads -> <=8 in flight
      asm volatile("s_waitcnt vmcnt(4)" ::: "memory");   // own tile-t landed
    } else {
      asm volatile("s_waitcnt vmcnt(0)" ::: "memory");   // last tile: drain
    }
    __builtin_amdgcn_s_barrier();              // all waves' tile-t loads landed

    if (kv0 <= qrow0w + 31) {                  // wave-uniform active guard
      const char* Kb = (const char*)Ks[t & 1];
      const char* Vb = (const char*)Vs[t & 1];

      f32x16 sa[2];
#pragma unroll
      for (int i = 0; i < 2; ++i)
#pragma unroll
        for (int r = 0; r < 16; ++r) sa[i][r] = 0.f;

      __builtin_amdgcn_s_setprio(1);
#pragma unroll
      for (int i = 0; i < 2; ++i) {
        const int row = 32 * i + l31;          // kv row in tile
        const int rb = row << 7, rx = row & 7;
#pragma unroll
        for (int kbI = 0; kbI < 4; ++kbI) {
          const short8 ak = *(const short8*)(Kb + rb + ((((kbI << 1) | hi) ^ rx) << 4));
          sa[i] = __builtin_amdgcn_mfma_f32_32x32x16_bf16(ak, bq[kbI], sa[i], 0, 0, 0);
        }
      }
      __builtin_amdgcn_s_setprio(0);

      if (kv0 + 63 > qrow0w) {
#pragma unroll
        for (int i = 0; i < 2; ++i) {
          const int kvb = kv0 + 32 * i + 4 * hi;
#pragma unroll
          for (int r = 0; r < 16; ++r)
            if (kvb + (r & 3) + 8 * (r >> 2) > qg) sa[i][r] = -INFINITY;
        }
      }

      float tmax = sa[0][0];
#pragma unroll
      for (int i = 0; i < 2; ++i)
#pragma unroll
        for (int r = 0; r < 16; ++r) tmax = fmaxf(tmax, sa[i][r]);
      tmax = fmaxf(tmax, __shfl_xor(tmax, 32));
      if (!__all(tmax <= m + 8.0f)) {
        const float mn = fmaxf(m, tmax);
        const float al = fexp2(m - mn);
        m = mn;
        lsum *= al;
#pragma unroll
        for (int a2 = 0; a2 < 2; ++a2)
#pragma unroll
          for (int r = 0; r < 16; ++r) ota[a2][r] *= al;
      }
      float rs = 0.f;
#pragma unroll
      for (int i = 0; i < 2; ++i)
#pragma unroll
        for (int r = 0; r < 16; ++r) {
          const float p = fexp2(sa[i][r] - m);
          sa[i][r] = p;
          rs += p;
        }
      rs += __shfl_xor(rs, 32);
      lsum += rs;

      short8 bp[4];
#pragma unroll
      for (int i = 0; i < 2; ++i)
#pragma unroll
        for (int jh = 0; jh < 2; ++jh) {
          const int bs = 8 * jh;
          const unsigned x0 = cvt_pk_bf16(sa[i][bs + 0], sa[i][bs + 1]);
          const unsigned y0 = cvt_pk_bf16(sa[i][bs + 4], sa[i][bs + 5]);
          const unsigned x1 = cvt_pk_bf16(sa[i][bs + 2], sa[i][bs + 3]);
          const unsigned y1 = cvt_pk_bf16(sa[i][bs + 6], sa[i][bs + 7]);
          const uint2v s0 = __builtin_amdgcn_permlane32_swap(x0, y0, false, false);
          const uint2v s1 = __builtin_amdgcn_permlane32_swap(x1, y1, false, false);
          union { uint4v u4; short8 s; } bb;
          bb.u4[0] = s0[0]; bb.u4[1] = s1[0]; bb.u4[2] = s0[1]; bb.u4[3] = s1[1];
          bp[2 * i + jh] = bb.s;
        }

      __builtin_amdgcn_s_setprio(1);
#pragma unroll
      for (int a2 = 0; a2 < 2; ++a2) {
        const int row = 32 * a2 + l31;         // d row
        const int rb = row << 7, rx = row & 7;
#pragma unroll
        for (int kf = 0; kf < 4; ++kf) {
          const short8 av = *(const short8*)(Vb + rb + ((((kf << 1) | hi) ^ rx) << 4));
          ota[a2] = __builtin_amdgcn_mfma_f32_32x32x16_bf16(av, bp[kf], ota[a2], 0, 0, 0);
        }
      }
      __builtin_amdgcn_s_setprio(0);
    }

    asm volatile("" ::: "memory");             // keep ds_reads on this side
    __builtin_amdgcn_s_barrier();              // WAR: reads done before next STAGE
  }
#undef STAGE

  const int b = bh >> 4, h = bh & 15;
  unsigned short* cb = ctx + (((long)b * SEQ) << 10) + (h << 6);
  const float inv = 1.0f / lsum;
  const long trow = qg;
#pragma unroll
  for (int a2 = 0; a2 < 2; ++a2)
#pragma unroll
    for (int rb4 = 0; rb4 < 4; ++rb4) {
      const int d0 = 32 * a2 + 8 * rb4 + 4 * hi;
      uint2v pk;
      pk[0] = cvt_pk_bf16(ota[a2][4 * rb4 + 0] * inv, ota[a2][4 * rb4 + 1] * inv);
      pk[1] = cvt_pk_bf16(ota[a2][4 * rb4 + 2] * inv, ota[a2][4 * rb4 + 3] * inv);
      *(uint2v*)(cb + trow * D_MODEL + d0) = pk;
    }
}

// ---------------------------------------------------------------------------
extern "C" void kernel_launch(void* const* d_in, const int* in_sizes, int n_in,
                              void* d_out, int out_size, void* d_ws, size_t ws_size,
                              hipStream_t stream) {
  const float* x  = (const float*)d_in[0];
  const float* wq = (const float*)d_in[1];
  const float* wk = (const float*)d_in[2];
  const float* wv = (const float*)d_in[3];
  const float* wo = (const float*)d_in[4];
  float* out = (float*)d_out;
  char* ws = (char*)d_ws;

  unsigned short* xb  = (unsigned short*)(ws);                 // 16 MB (x bf16; reused as ctx)
  unsigned short* wb  = (unsigned short*)(ws + (16l << 20));   // 8 MB  (Wq|Wk|Wv|Wo bf16)
  unsigned short* qb  = (unsigned short*)(ws + (24l << 20));   // 16 MB [bh][t][d]
  unsigned short* kb  = (unsigned short*)(ws + (40l << 20));   // 16 MB [bh][t][d]
  unsigned short* vt  = (unsigned short*)(ws + (56l << 20));   // 16 MB [bh][d][t]
  float* cosT = (float*)(ws + (72l << 20));                    // 256 KB [j][t]
  float* sinT = cosT + SEQ * 32;                               // 256 KB [j][t]
  unsigned short* ctx = xb;   // xb dead after QKV GEMM

  const long nthreads = (long)NCONV_THREADS + (long)SEQ * 32;  // conv + tables
  k_prep<<<dim3((unsigned)((nthreads + 255) / 256)), dim3(256), 0, stream>>>(
      x, wq, wk, wv, wo, xb, wb, cosT, sinT);
  k_gemm<0><<<dim3(64, 24), dim3(256), 0, stream>>>(
      xb, wb, qb, kb, vt, cosT, sinT, nullptr);
  k_attn<<<dim3(1024), dim3(256), 0, stream>>>(qb, kb, vt, ctx);
  k_gemm<1><<<dim3(64, 8), dim3(256), 0, stream>>>(
      ctx, wb + 3l * D_MODEL * D_MODEL, nullptr, nullptr, nullptr, nullptr, nullptr, out);
}

// Round 15
// 156.666 us; speedup vs baseline: 1.3317x; 1.0279x over previous
//
#include <hip/hip_runtime.h>
#include <hip/hip_bf16.h>
#include <stdint.h>
#include <math.h>

#define D_MODEL 1024
#define NH 16
#define HD 64
#define BATCH 4
#define SEQ 2048
#define MTOT (BATCH*SEQ)   // 8192
#define NBH (BATCH*NH)     // 64

typedef __attribute__((ext_vector_type(8))) short short8;    // 8 bf16
typedef __attribute__((ext_vector_type(4))) short short4v;   // 4 bf16
typedef __attribute__((ext_vector_type(2))) unsigned uint2v;
typedef __attribute__((ext_vector_type(4))) unsigned uint4v;
typedef __attribute__((ext_vector_type(4))) float f32x4;
typedef __attribute__((ext_vector_type(16))) float f32x16;

static __device__ __forceinline__ unsigned short f2bf(float f) {
  union { float f; unsigned u; } v; v.f = f;
  unsigned r = v.u + 0x7FFFu + ((v.u >> 16) & 1u);   // RNE
  return (unsigned short)(r >> 16);
}

// HW packed f32x2 -> bf16x2 (RNE); no builtin on gfx950 -> inline asm (T12)
static __device__ __forceinline__ unsigned cvt_pk_bf16(float lo, float hi) {
  unsigned r;
  asm("v_cvt_pk_bf16_f32 %0, %1, %2" : "=v"(r) : "v"(lo), "v"(hi));
  return r;
}

static __device__ __forceinline__ float fexp2(float x) {
#if __has_builtin(__builtin_amdgcn_exp2f)
  return __builtin_amdgcn_exp2f(x);
#else
  return __expf(x * 0.69314718056f);
#endif
}

#define GLOAD16(g, l) __builtin_amdgcn_global_load_lds( \
    (const __attribute__((address_space(1))) unsigned int*)(g), \
    (__attribute__((address_space(3))) unsigned int*)(l), 16, 0, 0)

// ---------------------------------------------------------------------------
// K0: convert x and weights to bf16 (float4 loads, packed bf16x2 stores —
// 16B/lane in, 8B/lane out), build RoPE tables ([j][t], t fast).
// ---------------------------------------------------------------------------
#define NCONV_THREADS 3145728   // (MTOT*D_MODEL + 4*D_MODEL*D_MODEL) / 4
__global__ __launch_bounds__(256) void k_prep(
    const float* __restrict__ x, const float* __restrict__ wq,
    const float* __restrict__ wk, const float* __restrict__ wv,
    const float* __restrict__ wo,
    unsigned short* __restrict__ xb, unsigned short* __restrict__ wb,
    float* __restrict__ cosT, float* __restrict__ sinT) {
  const long gid = (long)blockIdx.x * 256 + threadIdx.x;
  const long NX = (long)MTOT * D_MODEL;      // 8388608
  const long NW = (long)D_MODEL * D_MODEL;   // 1048576
  if (gid < NCONV_THREADS) {
    const long e0 = gid << 2;                // first of 4 elements
    const float* src;
    unsigned short* dst;
    if (e0 < NX) {
      src = x + e0;
      dst = xb + e0;
    } else {
      const long j = e0 - NX;                // 0 .. 4*NW-1
      const int w = (int)(j >> 20);          // NW = 2^20
      const long off = j & (NW - 1);
      src = (w == 0 ? wq : w == 1 ? wk : w == 2 ? wv : wo) + off;
      dst = wb + j;                          // wb = [Wq|Wk|Wv|Wo] contiguous
    }
    const f32x4 v = *(const f32x4*)src;
    uint2v pk;
    pk[0] = cvt_pk_bf16(v[0], v[1]);
    pk[1] = cvt_pk_bf16(v[2], v[3]);
    *(uint2v*)dst = pk;
    return;
  }
  const long tt = gid - NCONV_THREADS;       // 0 .. SEQ*32-1
  if (tt < (long)SEQ * 32) {
    const int t = (int)(tt & (SEQ - 1)), j = (int)(tt >> 11);
    const float freq = 1.0f / powf(10000.0f, (float)j * (1.0f / 32.0f));
    const float ang = (float)t * freq;
    cosT[j * SEQ + t] = cosf(ang);
    sinT[j * SEQ + t] = sinf(ang);
  }
}

// ---------------------------------------------------------------------------
// GEMM: C[m][n] = sum_k A[m][k] * Bw[n][k]
// THIS ROUND: BK 32 -> 64, single-buffered (32KB LDS, 5 blocks/CU).
// Halves the per-block barrier count (64 -> 32) and vmcnt(0) drain count
// (32 -> 16) at identical per-K ds_read/MFMA density — attacks the
// drain+barrier-skew residual without the R13 occupancy collapse.
// Swizzle (T2/rule#21) re-derived for 128B rows (8 chunks of 16B):
// chunk c' = c ^ (row&7); source pre-swizzled ((row&7) const across a
// thread's 4 granules), ds_read applies the same XOR.
// EPI=0 (QKV): RoPE fused, V stored transposed. EPI=1: fp32 out.
// ---------------------------------------------------------------------------
#define MFMA16(a, b, c) __builtin_amdgcn_mfma_f32_16x16x32_bf16(a, b, c, 0, 0, 0)

template<int EPI>
__global__ __launch_bounds__(256) void k_gemm(
    const unsigned short* __restrict__ A, const unsigned short* __restrict__ Bw,
    unsigned short* __restrict__ q, unsigned short* __restrict__ k2,
    unsigned short* __restrict__ vt,
    const float* __restrict__ cosT, const float* __restrict__ sinT,
    float* __restrict__ outf) {
  __shared__ __align__(16) unsigned short As[128 * 64];   // 16KB
  __shared__ __align__(16) unsigned short Bs[128 * 64];   // 16KB
  const int tid = threadIdx.x;
  const int wid = tid >> 6, lane = tid & 63;
  const int l15 = lane & 15, lq = lane >> 4;
  const int m0 = blockIdx.x * 128, n0 = blockIdx.y * 128;
  const int wm = (wid >> 1) * 64, wn = (wid & 1) * 64;

  const f32x4 fz = {0.f, 0.f, 0.f, 0.f};
  f32x4 acc[4][4];
#pragma unroll
  for (int i = 0; i < 4; ++i)
#pragma unroll
    for (int j = 0; j < 4; ++j) acc[i][j] = fz;

  // staging: granule s covers row sr+32s (s=0..3), chunk sc (16B units).
  // source chunk pre-swizzled: scs = sc ^ (sr&7); (sr+32s)&7 == sr&7.
  const int sr = tid >> 3;                     // 0..31
  const int scs = (tid & 7) ^ (sr & 7);
  const unsigned short* Ag = A + (long)(m0 + sr) * D_MODEL + scs * 8;
  const unsigned short* Bg = Bw + (long)(n0 + sr) * D_MODEL + scs * 8;
  // LDS dest: wave w granule s -> As + w*512 + s*2048 (8 rows x 128B, linear)

  const int rsw = l15 & 7;                     // read-side row swizzle key

  for (int k0 = 0; k0 < D_MODEL; k0 += 64) {
#pragma unroll
    for (int s = 0; s < 4; ++s) {
      GLOAD16(Ag + k0 + (long)(32 * s) * D_MODEL, As + wid * 512 + s * 2048);
      GLOAD16(Bg + k0 + (long)(32 * s) * D_MODEL, Bs + wid * 512 + s * 2048);
    }
    __syncthreads();   // drains vmcnt (global_load_lds) + publishes block-wide

#pragma unroll
    for (int kk = 0; kk < 2; ++kk) {
      short8 af[4], bf[4];
#pragma unroll
      for (int i = 0; i < 4; ++i) {
        const int ra = wm + i * 16 + l15;
        const int rb = wn + i * 16 + l15;
        af[i] = *(const short8*)(As + ra * 64 + ((((kk << 2) | lq) ^ (ra & 7)) << 3));
        bf[i] = *(const short8*)(Bs + rb * 64 + ((((kk << 2) | lq) ^ (rb & 7)) << 3));
      }
#pragma unroll
      for (int i = 0; i < 4; ++i)
#pragma unroll
        for (int j = 0; j < 4; ++j)
          acc[i][j] = MFMA16(af[i], bf[j], acc[i][j]);
    }
    __syncthreads();   // WAR: reads done before next stage overwrites
  }

#pragma unroll
  for (int i = 0; i < 4; ++i) {
#pragma unroll
    for (int j = 0; j < 4; ++j) {
      if (EPI == 1) {
#pragma unroll
        for (int r = 0; r < 4; ++r) {
          const int m = m0 + wm + i * 16 + lq * 4 + r;
          const int n = n0 + wn + j * 16 + l15;
          outf[(long)m * D_MODEL + n] = acc[i][j][r];
        }
      } else {
        const int n = n0 + wn + j * 16 + l15;       // sel uniform over wave
        const int sel = n >> 10, nl = n & 1023;
        const int hh = nl >> 6, dd = nl & 63;
        const int mb = m0 + wm + i * 16 + lq * 4;   // 4 consecutive t
        const int bb = mb >> 11, t0 = mb & (SEQ - 1);
        const long bh = (long)bb * NH + hh;
        if (sel == 2) {
          uint2v pk;
          pk[0] = cvt_pk_bf16(acc[i][j][0], acc[i][j][1]);
          pk[1] = cvt_pk_bf16(acc[i][j][2], acc[i][j][3]);
          *(uint2v*)(vt + (bh * HD + dd) * SEQ + t0) = pk;   // V^T: [bh][d][t]
        } else {
          unsigned short* dst = (sel == 0) ? q : k2;
          const float qs = (sel == 0) ? 0.18033688011112793f : 1.0f;  // 0.125*log2e
          const float sgn = (dd & 1) ? 1.f : -1.f;
          const int jt = dd >> 1;
          const f32x4 cv = *(const f32x4*)(cosT + jt * SEQ + t0);
          const f32x4 sv = *(const f32x4*)(sinT + jt * SEQ + t0);
#pragma unroll
          for (int r = 0; r < 4; ++r) {
            const float val = acc[i][j][r];
            const float p = __shfl_xor(val, 1);     // RoPE pair partner (n^1)
            dst[((bh * SEQ + t0 + r) << 6) + dd] = f2bf((val * cv[r] + sgn * sv[r] * p) * qs);
          }
        }
      }
    }
  }
}

// ---------------------------------------------------------------------------
// K4: causal flash attention, swapped-operand, 32x32x16 MFMA, in-register P,
// counted-vmcnt dual-barrier schedule + makespan-constant remap (R10, proven).
// ---------------------------------------------------------------------------
__global__ __launch_bounds__(256, 3) void k_attn(
    const unsigned short* __restrict__ qb, const unsigned short* __restrict__ kb,
    const unsigned short* __restrict__ vt, unsigned short* __restrict__ ctx) {
  __shared__ __align__(16) unsigned short Ks[2][4096];   // [64 kv][64 d] swizzled
  __shared__ __align__(16) unsigned short Vs[2][4096];   // [64 d][64 kv] swizzled

  // makespan-constant remap (bijective orig -> (bh, blk))
  const int orig = blockIdx.x;                 // 0..1023
  const int c = orig & 255, rr = orig >> 8;    // co-resident group, round
  const int x = c & 7, y = c >> 3;             // XCD slot, class
  const int u = y & 3, g = y >> 2;
  const int bh = x * 8 + g;                    // 8 bh per XCD slot
  const int blk = (rr & 1) ? (15 - ((rr >> 1) << 2) - u)
                           : (u + ((rr >> 1) << 2));   // {u,15-u,u+4,11-u}
  const int ntB = 2 * blk + 2;

  const int tid = threadIdx.x;
  const int wid = tid >> 6, lane = tid & 63;
  const int l31 = lane & 31, hi = lane >> 5;
  const int qrow0w = blk * 128 + wid * 32;
  const int qg = qrow0w + l31;                 // this lane's q row

  const unsigned short* Kg = kb + ((long)bh * SEQ << 6);
  const unsigned short* Vg = vt + (long)bh * HD * SEQ;

  const int r0 = tid >> 3, c0 = tid & 7;
  const int r1 = r0 + 32;
  const int cs = c0 ^ (r0 & 7);                // r1&7 == r0&7

  const unsigned short* Qrow = qb + (((long)bh * SEQ + qrow0w + l31) << 6);
  short8 bq[4];
#pragma unroll
  for (int kbI = 0; kbI < 4; ++kbI)
    bq[kbI] = *(const short8*)(Qrow + kbI * 16 + hi * 8);

  f32x16 ota[2];                               // O^T: d = 32*a2 + (r&3)+8(r>>2)+4hi, q = l31
#pragma unroll
  for (int a2 = 0; a2 < 2; ++a2)
#pragma unroll
    for (int r = 0; r < 16; ++r) ota[a2][r] = 0.f;
  float m = -INFINITY, lsum = 0.f;

#define STAGE(t_) { \
    const long kv0s = (long)((t_) << 6); \
    unsigned short* kd = Ks[(t_) & 1]; \
    unsigned short* vd = Vs[(t_) & 1]; \
    GLOAD16(Kg + ((kv0s + r0) << 6) + (cs << 3), kd + wid * 512); \
    GLOAD16(Kg + ((kv0s + r1) << 6) + (cs << 3), kd + 2048 + wid * 512); \
    GLOAD16(Vg + (long)r0 * SEQ + kv0s + (cs << 3), vd + wid * 512); \
    GLOAD16(Vg + (long)r1 * SEQ + kv0s + (cs << 3), vd + 2048 + wid * 512); \
  }

  STAGE(0);

  for (int t = 0; t < ntB; ++t) {
    const int kv0 = t << 6;
    if (t + 1 < ntB) {
      STAGE(t + 1);                            // 4 more loads -> <=8 in flight
      asm volatile("s_waitcnt vmcnt(4)" ::: "memory");   // own tile-t landed
    } else {
      asm volatile("s_waitcnt vmcnt(0)" ::: "memory");   // last tile: drain
    }
    __builtin_amdgcn_s_barrier();              // all waves' tile-t loads landed

    if (kv0 <= qrow0w + 31) {                  // wave-uniform active guard
      const char* Kb = (const char*)Ks[t & 1];
      const char* Vb = (const char*)Vs[t & 1];

      f32x16 sa[2];
#pragma unroll
      for (int i = 0; i < 2; ++i)
#pragma unroll
        for (int r = 0; r < 16; ++r) sa[i][r] = 0.f;

      __builtin_amdgcn_s_setprio(1);
#pragma unroll
      for (int i = 0; i < 2; ++i) {
        const int row = 32 * i + l31;          // kv row in tile
        const int rb = row << 7, rx = row & 7;
#pragma unroll
        for (int kbI = 0; kbI < 4; ++kbI) {
          const short8 ak = *(const short8*)(Kb + rb + ((((kbI << 1) | hi) ^ rx) << 4));
          sa[i] = __builtin_amdgcn_mfma_f32_32x32x16_bf16(ak, bq[kbI], sa[i], 0, 0, 0);
        }
      }
      __builtin_amdgcn_s_setprio(0);

      if (kv0 + 63 > qrow0w) {
#pragma unroll
        for (int i = 0; i < 2; ++i) {
          const int kvb = kv0 + 32 * i + 4 * hi;
#pragma unroll
          for (int r = 0; r < 16; ++r)
            if (kvb + (r & 3) + 8 * (r >> 2) > qg) sa[i][r] = -INFINITY;
        }
      }

      float tmax = sa[0][0];
#pragma unroll
      for (int i = 0; i < 2; ++i)
#pragma unroll
        for (int r = 0; r < 16; ++r) tmax = fmaxf(tmax, sa[i][r]);
      tmax = fmaxf(tmax, __shfl_xor(tmax, 32));
      if (!__all(tmax <= m + 8.0f)) {
        const float mn = fmaxf(m, tmax);
        const float al = fexp2(m - mn);
        m = mn;
        lsum *= al;
#pragma unroll
        for (int a2 = 0; a2 < 2; ++a2)
#pragma unroll
          for (int r = 0; r < 16; ++r) ota[a2][r] *= al;
      }
      float rs = 0.f;
#pragma unroll
      for (int i = 0; i < 2; ++i)
#pragma unroll
        for (int r = 0; r < 16; ++r) {
          const float p = fexp2(sa[i][r] - m);
          sa[i][r] = p;
          rs += p;
        }
      rs += __shfl_xor(rs, 32);
      lsum += rs;

      short8 bp[4];
#pragma unroll
      for (int i = 0; i < 2; ++i)
#pragma unroll
        for (int jh = 0; jh < 2; ++jh) {
          const int bs = 8 * jh;
          const unsigned x0 = cvt_pk_bf16(sa[i][bs + 0], sa[i][bs + 1]);
          const unsigned y0 = cvt_pk_bf16(sa[i][bs + 4], sa[i][bs + 5]);
          const unsigned x1 = cvt_pk_bf16(sa[i][bs + 2], sa[i][bs + 3]);
          const unsigned y1 = cvt_pk_bf16(sa[i][bs + 6], sa[i][bs + 7]);
          const uint2v s0 = __builtin_amdgcn_permlane32_swap(x0, y0, false, false);
          const uint2v s1 = __builtin_amdgcn_permlane32_swap(x1, y1, false, false);
          union { uint4v u4; short8 s; } bb;
          bb.u4[0] = s0[0]; bb.u4[1] = s1[0]; bb.u4[2] = s0[1]; bb.u4[3] = s1[1];
          bp[2 * i + jh] = bb.s;
        }

      __builtin_amdgcn_s_setprio(1);
#pragma unroll
      for (int a2 = 0; a2 < 2; ++a2) {
        const int row = 32 * a2 + l31;         // d row
        const int rb = row << 7, rx = row & 7;
#pragma unroll
        for (int kf = 0; kf < 4; ++kf) {
          const short8 av = *(const short8*)(Vb + rb + ((((kf << 1) | hi) ^ rx) << 4));
          ota[a2] = __builtin_amdgcn_mfma_f32_32x32x16_bf16(av, bp[kf], ota[a2], 0, 0, 0);
        }
      }
      __builtin_amdgcn_s_setprio(0);
    }

    asm volatile("" ::: "memory");             // keep ds_reads on this side
    __builtin_amdgcn_s_barrier();              // WAR: reads done before next STAGE
  }
#undef STAGE

  const int b = bh >> 4, h = bh & 15;
  unsigned short* cb = ctx + (((long)b * SEQ) << 10) + (h << 6);
  const float inv = 1.0f / lsum;
  const long trow = qg;
#pragma unroll
  for (int a2 = 0; a2 < 2; ++a2)
#pragma unroll
    for (int rb4 = 0; rb4 < 4; ++rb4) {
      const int d0 = 32 * a2 + 8 * rb4 + 4 * hi;
      uint2v pk;
      pk[0] = cvt_pk_bf16(ota[a2][4 * rb4 + 0] * inv, ota[a2][4 * rb4 + 1] * inv);
      pk[1] = cvt_pk_bf16(ota[a2][4 * rb4 + 2] * inv, ota[a2][4 * rb4 + 3] * inv);
      *(uint2v*)(cb + trow * D_MODEL + d0) = pk;
    }
}

// ---------------------------------------------------------------------------
extern "C" void kernel_launch(void* const* d_in, const int* in_sizes, int n_in,
                              void* d_out, int out_size, void* d_ws, size_t ws_size,
                              hipStream_t stream) {
  const float* x  = (const float*)d_in[0];
  const float* wq = (const float*)d_in[1];
  const float* wk = (const float*)d_in[2];
  const float* wv = (const float*)d_in[3];
  const float* wo = (const float*)d_in[4];
  float* out = (float*)d_out;
  char* ws = (char*)d_ws;

  unsigned short* xb  = (unsigned short*)(ws);                 // 16 MB (x bf16; reused as ctx)
  unsigned short* wb  = (unsigned short*)(ws + (16l << 20));   // 8 MB  (Wq|Wk|Wv|Wo bf16)
  unsigned short* qb  = (unsigned short*)(ws + (24l << 20));   // 16 MB [bh][t][d]
  unsigned short* kb  = (unsigned short*)(ws + (40l << 20));   // 16 MB [bh][t][d]
  unsigned short* vt  = (unsigned short*)(ws + (56l << 20));   // 16 MB [bh][d][t]
  float* cosT = (float*)(ws + (72l << 20));                    // 256 KB [j][t]
  float* sinT = cosT + SEQ * 32;                               // 256 KB [j][t]
  unsigned short* ctx = xb;   // xb dead after QKV GEMM

  const long nthreads = (long)NCONV_THREADS + (long)SEQ * 32;  // conv + tables
  k_prep<<<dim3((unsigned)((nthreads + 255) / 256)), dim3(256), 0, stream>>>(
      x, wq, wk, wv, wo, xb, wb, cosT, sinT);
  k_gemm<0><<<dim3(64, 24), dim3(256), 0, stream>>>(
      xb, wb, qb, kb, vt, cosT, sinT, nullptr);
  k_attn<<<dim3(1024), dim3(256), 0, stream>>>(qb, kb, vt, ctx);
  k_gemm<1><<<dim3(64, 8), dim3(256), 0, stream>>>(
      ctx, wb + 3l * D_MODEL * D_MODEL, nullptr, nullptr, nullptr, nullptr, nullptr, out);
}